// Round 3
// baseline (1111.358 us; speedup 1.0000x reference)
//
#include <hip/hip_runtime.h>
#include <hip/hip_bf16.h>
#include <math.h>

#define D_DIM 2048
#define F_DIM 1408
#define FS_DIM 2816
#define E_NUM 8
#define N_TOK 2048
#define BK 32
#define LDSW 40   // LDS row stride in shorts: 80B, 16B-aligned, 20-bank stride

typedef __attribute__((ext_vector_type(8))) short bf16x8;
typedef __attribute__((ext_vector_type(4))) float f32x4;

__device__ inline short f2bf(float f) {
    __hip_bfloat16 h = __float2bfloat16(f);
    return *reinterpret_cast<short*>(&h);
}

__device__ inline float silu1(float v) { return v / (1.f + expf(-v)); }

__global__ __launch_bounds__(64) void zero_counts_kernel(int* c) {
    if (threadIdx.x < E_NUM) c[threadIdx.x] = 0;
}

// One wave per token: logits = x @ gate_w, softmax, top-2, per-expert lists.
__global__ __launch_bounds__(256) void gate_kernel(
    const float* __restrict__ x, const float* __restrict__ gw,
    float* __restrict__ assign_w, int* __restrict__ expert_count,
    int* __restrict__ expert_list)
{
    int wid = (blockIdx.x * 256 + threadIdx.x) >> 6;
    int lane = threadIdx.x & 63;
    if (wid >= N_TOK) return;
    const float* xr = x + (size_t)wid * D_DIM;
    float p[E_NUM];
#pragma unroll
    for (int e = 0; e < E_NUM; ++e) p[e] = 0.f;
    for (int d = lane; d < D_DIM; d += 64) {
        float xv = xr[d];
        const float4* g = reinterpret_cast<const float4*>(gw + (size_t)d * E_NUM);
        float4 g0 = g[0], g1 = g[1];
        p[0] = fmaf(xv, g0.x, p[0]); p[1] = fmaf(xv, g0.y, p[1]);
        p[2] = fmaf(xv, g0.z, p[2]); p[3] = fmaf(xv, g0.w, p[3]);
        p[4] = fmaf(xv, g1.x, p[4]); p[5] = fmaf(xv, g1.y, p[5]);
        p[6] = fmaf(xv, g1.z, p[6]); p[7] = fmaf(xv, g1.w, p[7]);
    }
#pragma unroll
    for (int off = 32; off > 0; off >>= 1)
#pragma unroll
        for (int e = 0; e < E_NUM; ++e)
            p[e] += __shfl_xor(p[e], off, 64);
    if (lane == 0) {
        float m = p[0];
#pragma unroll
        for (int e = 1; e < E_NUM; ++e) m = fmaxf(m, p[e]);
        float s = 0.f, pr[E_NUM];
#pragma unroll
        for (int e = 0; e < E_NUM; ++e) { pr[e] = expf(p[e] - m); s += pr[e]; }
        float inv = 1.f / s;
#pragma unroll
        for (int e = 0; e < E_NUM; ++e) pr[e] *= inv;
        int i0 = 0;
#pragma unroll
        for (int e = 1; e < E_NUM; ++e) if (pr[e] > pr[i0]) i0 = e;
        int i1 = (i0 == 0) ? 1 : 0;
#pragma unroll
        for (int e = 0; e < E_NUM; ++e) if (e != i0 && pr[e] > pr[i1]) i1 = e;
        int s0 = wid * 2, s1 = wid * 2 + 1;
        assign_w[s0] = pr[i0];
        assign_w[s1] = pr[i1];
        int p0 = atomicAdd(&expert_count[i0], 1);
        expert_list[i0 * N_TOK + p0] = s0;
        int p1 = atomicAdd(&expert_count[i1], 1);
        expert_list[i1 * N_TOK + p1] = s1;
    }
}

// Fused SwiGLU input GEMM (MFMA): H[row] = bf16(silu(A@W1) * (A@W3)).
// Tile 64x128, BK=32, 4 waves in 2x2. A fp32 (converted), W fp32 (converted),
// H bf16. GATHER: rows via expert_list (slot>>1 = token), H row = slot.
template<bool GATHER>
__global__ __launch_bounds__(256) void ffn_in_mfma(
    const float* __restrict__ X,
    const float* __restrict__ W1,
    const float* __restrict__ W3,
    short* __restrict__ H,          // bf16 out, leading dim = ldB
    int ldB,
    const int* __restrict__ expert_list,
    const int* __restrict__ expert_count)
{
    __shared__ short As[64][LDSW];
    __shared__ short Bs1[128][LDSW];
    __shared__ short Bs3[128][LDSW];
    __shared__ int sl[64];

    int tid = threadIdx.x;
    int m0, count;
    const int* list = nullptr;
    if (GATHER) {
        int e = blockIdx.x >> 5;
        int mt = blockIdx.x & 31;
        count = expert_count[e];
        m0 = mt * 64;
        if (m0 >= count) return;
        list = expert_list + e * N_TOK;
        W1 += (size_t)e * D_DIM * F_DIM;
        W3 += (size_t)e * D_DIM * F_DIM;
    } else {
        m0 = blockIdx.x * 64;
        count = N_TOK;
    }
    int n0 = blockIdx.y * 128;

    if (tid < 64) {
        if (GATHER) {
            int r = m0 + tid;
            sl[tid] = (r < count) ? list[r] : -1;
        } else {
            sl[tid] = m0 + tid;
        }
    }
    __syncthreads();

    // A staging: thread -> (row = tid>>2, 8 k at (tid&3)*8)
    int arow = tid >> 2, akq = tid & 3;
    int sA = sl[arow];
    bool avalid = sA >= 0;
    int tokrow = avalid ? (GATHER ? (sA >> 1) : sA) : 0;
    const float* Aptr = X + (size_t)tokrow * D_DIM + akq * 8;
    // B staging (transposed to Bs[n][k]): thread -> n pair (tid&63)*2, k block (tid>>6)*8
    int bnn = (tid & 63) * 2;
    int bkb = (tid >> 6) * 8;
    const float* B1p = W1 + (size_t)bkb * ldB + n0 + bnn;
    const float* B3p = W3 + (size_t)bkb * ldB + n0 + bnn;

    int lane = tid & 63;
    int wv = tid >> 6;
    int wm = wv >> 1, wn = wv & 1;        // wave tile: rows wm*32, cols wn*64
    int frow = lane & 15, fkg = lane >> 4;

    f32x4 acc1[2][4], acc3[2][4];
#pragma unroll
    for (int i = 0; i < 2; ++i)
#pragma unroll
        for (int j = 0; j < 4; ++j) { acc1[i][j] = (f32x4)0.f; acc3[i][j] = (f32x4)0.f; }

    for (int k0 = 0; k0 < D_DIM; k0 += BK) {
        float4 a0 = make_float4(0, 0, 0, 0), a1 = make_float4(0, 0, 0, 0);
        if (avalid) {
            a0 = *reinterpret_cast<const float4*>(Aptr + k0);
            a1 = *reinterpret_cast<const float4*>(Aptr + k0 + 4);
        }
        float2 b1r[8], b3r[8];
#pragma unroll
        for (int j = 0; j < 8; ++j) {
            b1r[j] = *reinterpret_cast<const float2*>(B1p + (size_t)(k0 + j) * ldB);
            b3r[j] = *reinterpret_cast<const float2*>(B3p + (size_t)(k0 + j) * ldB);
        }
        __syncthreads();
        bf16x8 av;
        av[0] = f2bf(a0.x); av[1] = f2bf(a0.y); av[2] = f2bf(a0.z); av[3] = f2bf(a0.w);
        av[4] = f2bf(a1.x); av[5] = f2bf(a1.y); av[6] = f2bf(a1.z); av[7] = f2bf(a1.w);
        *reinterpret_cast<bf16x8*>(&As[arow][akq * 8]) = av;
        bf16x8 c0, c1, d0, d1;
#pragma unroll
        for (int j = 0; j < 8; ++j) {
            c0[j] = f2bf(b1r[j].x); c1[j] = f2bf(b1r[j].y);
            d0[j] = f2bf(b3r[j].x); d1[j] = f2bf(b3r[j].y);
        }
        *reinterpret_cast<bf16x8*>(&Bs1[bnn][bkb]) = c0;
        *reinterpret_cast<bf16x8*>(&Bs1[bnn + 1][bkb]) = c1;
        *reinterpret_cast<bf16x8*>(&Bs3[bnn][bkb]) = d0;
        *reinterpret_cast<bf16x8*>(&Bs3[bnn + 1][bkb]) = d1;
        __syncthreads();

        bf16x8 af[2], b1f[4], b3f[4];
#pragma unroll
        for (int mf = 0; mf < 2; ++mf)
            af[mf] = *reinterpret_cast<bf16x8*>(&As[wm * 32 + mf * 16 + frow][fkg * 8]);
#pragma unroll
        for (int nf = 0; nf < 4; ++nf) {
            b1f[nf] = *reinterpret_cast<bf16x8*>(&Bs1[wn * 64 + nf * 16 + frow][fkg * 8]);
            b3f[nf] = *reinterpret_cast<bf16x8*>(&Bs3[wn * 64 + nf * 16 + frow][fkg * 8]);
        }
#pragma unroll
        for (int mf = 0; mf < 2; ++mf)
#pragma unroll
            for (int nf = 0; nf < 4; ++nf) {
                acc1[mf][nf] = __builtin_amdgcn_mfma_f32_16x16x32_bf16(
                    af[mf], b1f[nf], acc1[mf][nf], 0, 0, 0);
                acc3[mf][nf] = __builtin_amdgcn_mfma_f32_16x16x32_bf16(
                    af[mf], b3f[nf], acc3[mf][nf], 0, 0, 0);
            }
    }

    // Epilogue: C row = (lane>>4)*4 + j, col = lane&15 (verified m89 mapping)
#pragma unroll
    for (int mf = 0; mf < 2; ++mf) {
#pragma unroll
        for (int j = 0; j < 4; ++j) {
            int rl = wm * 32 + mf * 16 + (lane >> 4) * 4 + j;
            int s = sl[rl];
            if (s < 0) continue;
            short* hp = H + (size_t)s * ldB + n0 + wn * 64 + frow;
#pragma unroll
            for (int nf = 0; nf < 4; ++nf) {
                float g = acc1[mf][nf][j];
                float u = acc3[mf][nf][j];
                hp[nf * 16] = f2bf(silu1(g) * u);
            }
        }
    }
}

// Output GEMM (MFMA): Out(fp32) = A(bf16 H) @ W2(fp32). Tile 64x128, BK=32.
template<bool GATHER>
__global__ __launch_bounds__(256) void ffn_out_mfma(
    const short* __restrict__ Hbuf,   // bf16, leading dim ldA
    const float* __restrict__ W2,
    float* __restrict__ Out,          // leading dim D_DIM
    int ldA, int kmax,
    const int* __restrict__ expert_list,
    const int* __restrict__ expert_count)
{
    __shared__ short As[64][LDSW];
    __shared__ short Bs[128][LDSW];
    __shared__ int sl[64];

    int tid = threadIdx.x;
    int m0, count;
    const int* list = nullptr;
    if (GATHER) {
        int e = blockIdx.x >> 5;
        int mt = blockIdx.x & 31;
        count = expert_count[e];
        m0 = mt * 64;
        if (m0 >= count) return;
        list = expert_list + e * N_TOK;
        W2 += (size_t)e * F_DIM * D_DIM;
    } else {
        m0 = blockIdx.x * 64;
        count = N_TOK;
    }
    int n0 = blockIdx.y * 128;

    if (tid < 64) {
        if (GATHER) {
            int r = m0 + tid;
            sl[tid] = (r < count) ? list[r] : -1;
        } else {
            sl[tid] = m0 + tid;
        }
    }
    __syncthreads();

    int arow = tid >> 2, akq = tid & 3;
    int sA = sl[arow];
    bool avalid = sA >= 0;
    int aIdx = avalid ? sA : 0;
    const short* Aptr = Hbuf + (size_t)aIdx * ldA + akq * 8;
    int bnn = (tid & 63) * 2;
    int bkb = (tid >> 6) * 8;
    const float* B2p = W2 + (size_t)bkb * D_DIM + n0 + bnn;

    int lane = tid & 63;
    int wv = tid >> 6;
    int wm = wv >> 1, wn = wv & 1;
    int frow = lane & 15, fkg = lane >> 4;

    f32x4 acc[2][4];
#pragma unroll
    for (int i = 0; i < 2; ++i)
#pragma unroll
        for (int j = 0; j < 4; ++j) acc[i][j] = (f32x4)0.f;

    for (int k0 = 0; k0 < kmax; k0 += BK) {
        bf16x8 av = (bf16x8)0;
        if (avalid) av = *reinterpret_cast<const bf16x8*>(Aptr + k0);
        float2 br[8];
#pragma unroll
        for (int j = 0; j < 8; ++j)
            br[j] = *reinterpret_cast<const float2*>(B2p + (size_t)(k0 + j) * D_DIM);
        __syncthreads();
        *reinterpret_cast<bf16x8*>(&As[arow][akq * 8]) = av;
        bf16x8 c0, c1;
#pragma unroll
        for (int j = 0; j < 8; ++j) { c0[j] = f2bf(br[j].x); c1[j] = f2bf(br[j].y); }
        *reinterpret_cast<bf16x8*>(&Bs[bnn][bkb]) = c0;
        *reinterpret_cast<bf16x8*>(&Bs[bnn + 1][bkb]) = c1;
        __syncthreads();

        bf16x8 af[2], bf[4];
#pragma unroll
        for (int mf = 0; mf < 2; ++mf)
            af[mf] = *reinterpret_cast<bf16x8*>(&As[wm * 32 + mf * 16 + frow][fkg * 8]);
#pragma unroll
        for (int nf = 0; nf < 4; ++nf)
            bf[nf] = *reinterpret_cast<bf16x8*>(&Bs[wn * 64 + nf * 16 + frow][fkg * 8]);
#pragma unroll
        for (int mf = 0; mf < 2; ++mf)
#pragma unroll
            for (int nf = 0; nf < 4; ++nf)
                acc[mf][nf] = __builtin_amdgcn_mfma_f32_16x16x32_bf16(
                    af[mf], bf[nf], acc[mf][nf], 0, 0, 0);
    }

#pragma unroll
    for (int mf = 0; mf < 2; ++mf) {
#pragma unroll
        for (int j = 0; j < 4; ++j) {
            int rl = wm * 32 + mf * 16 + (lane >> 4) * 4 + j;
            int s = sl[rl];
            if (s < 0) continue;
            float* op = Out + (size_t)s * D_DIM + n0 + wn * 64 + frow;
#pragma unroll
            for (int nf = 0; nf < 4; ++nf)
                op[nf * 16] = acc[mf][nf][j];
        }
    }
}

// Y[tok] += w0 * H2[2*tok] + w1 * H2[2*tok+1]  (deterministic, no atomics)
__global__ __launch_bounds__(256) void combine_kernel(
    float* __restrict__ Y, const float* __restrict__ H2,
    const float* __restrict__ assign_w)
{
    int tok = blockIdx.x;
    float w0 = assign_w[2 * tok];
    float w1 = assign_w[2 * tok + 1];
    const float4* h0 = reinterpret_cast<const float4*>(H2 + (size_t)(2 * tok) * D_DIM);
    const float4* h1 = reinterpret_cast<const float4*>(H2 + (size_t)(2 * tok + 1) * D_DIM);
    float4* y = reinterpret_cast<float4*>(Y + (size_t)tok * D_DIM);
#pragma unroll
    for (int i = 0; i < 2; ++i) {
        int idx = threadIdx.x + i * 256;
        float4 yv = y[idx];
        float4 a = h0[idx];
        float4 b = h1[idx];
        yv.x = fmaf(w0, a.x, fmaf(w1, b.x, yv.x));
        yv.y = fmaf(w0, a.y, fmaf(w1, b.y, yv.y));
        yv.z = fmaf(w0, a.z, fmaf(w1, b.z, yv.z));
        yv.w = fmaf(w0, a.w, fmaf(w1, b.w, yv.w));
        y[idx] = yv;
    }
}

extern "C" void kernel_launch(void* const* d_in, const int* in_sizes, int n_in,
                              void* d_out, int out_size, void* d_ws, size_t ws_size,
                              hipStream_t stream) {
    const float* x   = (const float*)d_in[0];
    const float* gw  = (const float*)d_in[1];
    const float* sw1 = (const float*)d_in[2];
    const float* sw2 = (const float*)d_in[3];
    const float* sw3 = (const float*)d_in[4];
    const float* rw1 = (const float*)d_in[5];
    const float* rw2 = (const float*)d_in[6];
    const float* rw3 = (const float*)d_in[7];
    float* Y = (float*)d_out;

    char* ws = (char*)d_ws;
    float* assign_w     = (float*)(ws);                      // 4096 floats
    int*   expert_count = (int*)(ws + 16384);                // 8 ints
    int*   expert_list  = (int*)(ws + 16384 + 256);          // 8*2048 ints
    short* H            = (short*)(ws + 131072);             // 5,767,168 bf16 (reused)
    float* H2           = (float*)(ws + 131072 + 11534336);  // 4096*2048 fp32

    zero_counts_kernel<<<1, 64, 0, stream>>>(expert_count);
    gate_kernel<<<N_TOK / 4, 256, 0, stream>>>(x, gw, assign_w, expert_count, expert_list);

    // Shared experts: H = bf16(silu(X@sw1)*(X@sw3)); Y = H@sw2
    ffn_in_mfma<false><<<dim3(N_TOK / 64, FS_DIM / 128), 256, 0, stream>>>(
        x, sw1, sw3, H, FS_DIM, nullptr, nullptr);
    ffn_out_mfma<false><<<dim3(N_TOK / 64, D_DIM / 128), 256, 0, stream>>>(
        H, sw2, Y, FS_DIM, FS_DIM, nullptr, nullptr);

    // Routed experts (top-2): gathered per-expert tiles -> H, then H2 per slot
    ffn_in_mfma<true><<<dim3(E_NUM * (N_TOK / 64), F_DIM / 128), 256, 0, stream>>>(
        x, rw1, rw3, H, F_DIM, expert_list, expert_count);
    ffn_out_mfma<true><<<dim3(E_NUM * (N_TOK / 64), D_DIM / 128), 256, 0, stream>>>(
        H, rw2, H2, F_DIM, F_DIM, expert_list, expert_count);

    // Deterministic weighted combine into Y
    combine_kernel<<<N_TOK, 256, 0, stream>>>(Y, H2, assign_w);
}

// Round 5
// 779.056 us; speedup vs baseline: 1.4265x; 1.4265x over previous
//
#include <hip/hip_runtime.h>
#include <hip/hip_bf16.h>
#include <math.h>

#define D_DIM 2048
#define F_DIM 1408
#define FS_DIM 2816
#define E_NUM 8
#define N_TOK 2048

typedef __attribute__((ext_vector_type(8))) short bf16x8;
typedef __attribute__((ext_vector_type(4))) float f32x4;

__device__ inline short f2bf(float f) {
    __hip_bfloat16 h = __float2bfloat16(f);
    return *reinterpret_cast<short*>(&h);
}
__device__ inline float silu1(float v) { return v / (1.f + expf(-v)); }

__device__ inline void async_copy16(const void* g, void* l) {
    __builtin_amdgcn_global_load_lds(
        (const __attribute__((address_space(1))) void*)g,
        (__attribute__((address_space(3))) void*)l, 16, 0, 0);
}

__global__ __launch_bounds__(64) void zero_counts_kernel(int* c) {
    if (threadIdx.x < E_NUM) c[threadIdx.x] = 0;
}

// ---------------- gate (reads fp32 x) ----------------
__global__ __launch_bounds__(256) void gate_kernel(
    const float* __restrict__ x, const float* __restrict__ gw,
    float* __restrict__ assign_w, int* __restrict__ expert_count,
    int* __restrict__ expert_list)
{
    int wid = (blockIdx.x * 256 + threadIdx.x) >> 6;
    int lane = threadIdx.x & 63;
    if (wid >= N_TOK) return;
    const float* xr = x + (size_t)wid * D_DIM;
    float p[E_NUM];
#pragma unroll
    for (int e = 0; e < E_NUM; ++e) p[e] = 0.f;
    for (int d = lane; d < D_DIM; d += 64) {
        float xv = xr[d];
        const float4* g = reinterpret_cast<const float4*>(gw + (size_t)d * E_NUM);
        float4 g0 = g[0], g1 = g[1];
        p[0] = fmaf(xv, g0.x, p[0]); p[1] = fmaf(xv, g0.y, p[1]);
        p[2] = fmaf(xv, g0.z, p[2]); p[3] = fmaf(xv, g0.w, p[3]);
        p[4] = fmaf(xv, g1.x, p[4]); p[5] = fmaf(xv, g1.y, p[5]);
        p[6] = fmaf(xv, g1.z, p[6]); p[7] = fmaf(xv, g1.w, p[7]);
    }
#pragma unroll
    for (int off = 32; off > 0; off >>= 1)
#pragma unroll
        for (int e = 0; e < E_NUM; ++e)
            p[e] += __shfl_xor(p[e], off, 64);
    if (lane == 0) {
        float m = p[0];
#pragma unroll
        for (int e = 1; e < E_NUM; ++e) m = fmaxf(m, p[e]);
        float s = 0.f, pr[E_NUM];
#pragma unroll
        for (int e = 0; e < E_NUM; ++e) { pr[e] = expf(p[e] - m); s += pr[e]; }
        float inv = 1.f / s;
#pragma unroll
        for (int e = 0; e < E_NUM; ++e) pr[e] *= inv;
        int i0 = 0;
#pragma unroll
        for (int e = 1; e < E_NUM; ++e) if (pr[e] > pr[i0]) i0 = e;
        int i1 = (i0 == 0) ? 1 : 0;
#pragma unroll
        for (int e = 0; e < E_NUM; ++e) if (e != i0 && pr[e] > pr[i1]) i1 = e;
        int s0 = wid * 2, s1 = wid * 2 + 1;
        assign_w[s0] = pr[i0];
        assign_w[s1] = pr[i1];
        int p0 = atomicAdd(&expert_count[i0], 1);
        expert_list[i0 * N_TOK + p0] = s0;
        int p1 = atomicAdd(&expert_count[i1], 1);
        expert_list[i1 * N_TOK + p1] = s1;
    }
}

// ---------------- converts ----------------
__global__ __launch_bounds__(256) void cvt_x_kernel(
    const float* __restrict__ in, short* __restrict__ out)
{
    int i = (blockIdx.x * 256 + threadIdx.x) * 8;
    float4 v0 = *reinterpret_cast<const float4*>(in + i);
    float4 v1 = *reinterpret_cast<const float4*>(in + i + 4);
    bf16x8 o;
    o[0] = f2bf(v0.x); o[1] = f2bf(v0.y); o[2] = f2bf(v0.z); o[3] = f2bf(v0.w);
    o[4] = f2bf(v1.x); o[5] = f2bf(v1.y); o[6] = f2bf(v1.z); o[7] = f2bf(v1.w);
    *reinterpret_cast<bf16x8*>(out + i) = o;
}

// out[b][n][k] = bf16(in[b][k][n]); K,N multiples of 64
__global__ __launch_bounds__(256) void transpose_cvt_kernel(
    const float* __restrict__ in, short* __restrict__ out, int K, int N)
{
    __shared__ float tile[64][65];
    int b = blockIdx.z;
    in  += (size_t)b * K * N;
    out += (size_t)b * N * K;
    int k0 = blockIdx.x * 64;
    int n0 = blockIdx.y * 64;
    int t = threadIdx.x;
    int tr = t >> 4;
    int tc4 = (t & 15) * 4;
#pragma unroll
    for (int i = 0; i < 4; ++i) {
        int r = tr + i * 16;
        float4 v = *reinterpret_cast<const float4*>(in + (size_t)(k0 + r) * N + n0 + tc4);
        tile[r][tc4 + 0] = v.x; tile[r][tc4 + 1] = v.y;
        tile[r][tc4 + 2] = v.z; tile[r][tc4 + 3] = v.w;
    }
    __syncthreads();
#pragma unroll
    for (int i = 0; i < 4; ++i) {
        int n = tr + i * 16;
        short4 s4;
        s4.x = f2bf(tile[tc4 + 0][n]);
        s4.y = f2bf(tile[tc4 + 1][n]);
        s4.z = f2bf(tile[tc4 + 2][n]);
        s4.w = f2bf(tile[tc4 + 3][n]);
        *reinterpret_cast<short4*>(out + (size_t)(n0 + n) * K + k0 + tc4) = s4;
    }
}

// ---------------- MFMA GEMMs (bf16 A, transposed bf16 B, global_load_lds) ----------------
// Tile 64(M)x128(N), BK=32. 4 waves, wave-tile 32x64 (2x4 16x16 frags).
// LDS rows are 64B; source addresses pre-swizzled by slot ^= (row>>2)&3,
// ds_read applies the same XOR -> ~2-way bank conflicts (free).

template<bool GATHER>
__global__ __launch_bounds__(256) void ffn_in2(
    const short* __restrict__ Xb,    // bf16 [*, K]
    const short* __restrict__ W1t,   // bf16 [N][K] (+ e*F*D for GATHER)
    const short* __restrict__ W3t,
    short* __restrict__ H,           // bf16 [row][ldH]
    int ldH, int K,
    const int* __restrict__ expert_list,
    const int* __restrict__ expert_count)
{
    __shared__ short As[64 * 32];
    __shared__ short Bs1[128 * 32];
    __shared__ short Bs3[128 * 32];
    __shared__ int sl[64];

    int tid = threadIdx.x;
    int m0;
    if (GATHER) {
        int e = blockIdx.x >> 5;
        int mt = blockIdx.x & 31;
        int count = expert_count[e];
        m0 = mt * 64;
        if (m0 >= count) return;
        const int* list = expert_list + e * N_TOK;
        if (tid < 64) { int r = m0 + tid; sl[tid] = (r < count) ? list[r] : -1; }
        W1t += (size_t)e * F_DIM * D_DIM;
        W3t += (size_t)e * F_DIM * D_DIM;
    } else {
        m0 = blockIdx.x * 64;
        if (tid < 64) sl[tid] = m0 + tid;
    }
    int n0 = blockIdx.y * 128;
    __syncthreads();

    int lane = tid & 63, w = tid >> 6;
    // A staging: 1 issue/wave, rows w*16 + (lane>>2)
    int ar = w * 16 + (lane >> 2);
    int aslot = lane & 3;
    int sA = sl[ar];
    int atok = GATHER ? (sA >= 0 ? (sA >> 1) : 0) : sA;
    const char* a_src = (const char*)(Xb + (size_t)atok * K)
                      + ((aslot ^ ((ar >> 2) & 3)) << 4);
    char* a_dst = (char*)As + w * 1024;
    // B staging: 2 issues/wave/matrix, rows w*32 + q*16 + (lane>>2)
    int br0 = w * 32 + (lane >> 2);
    int br1 = br0 + 16;
    int gb0 = (br0 >> 2) & 3, gb1 = (br1 >> 2) & 3;
    const char* b1_src0 = (const char*)(W1t + (size_t)(n0 + br0) * K) + ((aslot ^ gb0) << 4);
    const char* b1_src1 = (const char*)(W1t + (size_t)(n0 + br1) * K) + ((aslot ^ gb1) << 4);
    const char* b3_src0 = (const char*)(W3t + (size_t)(n0 + br0) * K) + ((aslot ^ gb0) << 4);
    const char* b3_src1 = (const char*)(W3t + (size_t)(n0 + br1) * K) + ((aslot ^ gb1) << 4);
    char* b1_dst0 = (char*)Bs1 + (w * 2 + 0) * 1024;
    char* b1_dst1 = (char*)Bs1 + (w * 2 + 1) * 1024;
    char* b3_dst0 = (char*)Bs3 + (w * 2 + 0) * 1024;
    char* b3_dst1 = (char*)Bs3 + (w * 2 + 1) * 1024;

    int wm = w >> 1, wn = w & 1;
    int frow = lane & 15, fkg = lane >> 4;
    int kslot = (fkg ^ ((frow >> 2) & 3)) << 4;

    f32x4 acc1[2][4], acc3[2][4];
#pragma unroll
    for (int i = 0; i < 2; ++i)
#pragma unroll
        for (int j = 0; j < 4; ++j) { acc1[i][j] = (f32x4)0.f; acc3[i][j] = (f32x4)0.f; }

    int KB = K * 2;
    for (int kb = 0; kb < KB; kb += 64) {
        async_copy16(a_src + kb, a_dst);
        async_copy16(b1_src0 + kb, b1_dst0);
        async_copy16(b1_src1 + kb, b1_dst1);
        async_copy16(b3_src0 + kb, b3_dst0);
        async_copy16(b3_src1 + kb, b3_dst1);
        __syncthreads();
        bf16x8 af[2], b1f[4], b3f[4];
#pragma unroll
        for (int mf = 0; mf < 2; ++mf) {
            int r = wm * 32 + mf * 16 + frow;
            af[mf] = *reinterpret_cast<bf16x8*>((char*)As + r * 64 + kslot);
        }
#pragma unroll
        for (int nf = 0; nf < 4; ++nf) {
            int rb = wn * 64 + nf * 16 + frow;
            b1f[nf] = *reinterpret_cast<bf16x8*>((char*)Bs1 + rb * 64 + kslot);
            b3f[nf] = *reinterpret_cast<bf16x8*>((char*)Bs3 + rb * 64 + kslot);
        }
#pragma unroll
        for (int mf = 0; mf < 2; ++mf)
#pragma unroll
            for (int nf = 0; nf < 4; ++nf) {
                acc1[mf][nf] = __builtin_amdgcn_mfma_f32_16x16x32_bf16(
                    af[mf], b1f[nf], acc1[mf][nf], 0, 0, 0);
                acc3[mf][nf] = __builtin_amdgcn_mfma_f32_16x16x32_bf16(
                    af[mf], b3f[nf], acc3[mf][nf], 0, 0, 0);
            }
        __syncthreads();
    }

#pragma unroll
    for (int mf = 0; mf < 2; ++mf) {
#pragma unroll
        for (int j = 0; j < 4; ++j) {
            int rl = wm * 32 + mf * 16 + fkg * 4 + j;
            int s = sl[rl];
            if (s < 0) continue;
            short* hp = H + (size_t)s * ldH + n0 + wn * 64 + frow;
#pragma unroll
            for (int nf = 0; nf < 4; ++nf)
                hp[nf * 16] = f2bf(silu1(acc1[mf][nf][j]) * acc3[mf][nf][j]);
        }
    }
}

template<bool GATHER>
__global__ __launch_bounds__(256) void ffn_out2(
    const short* __restrict__ Abuf,  // bf16 [row][K]
    const short* __restrict__ W2t,   // bf16 [D][K] (+ e*D*F for GATHER)
    float* __restrict__ Out,         // fp32 [row][D_DIM]
    int K,
    const int* __restrict__ expert_list,
    const int* __restrict__ expert_count)
{
    __shared__ short As[64 * 32];
    __shared__ short Bs[128 * 32];
    __shared__ int sl[64];

    int tid = threadIdx.x;
    int m0;
    if (GATHER) {
        int e = blockIdx.x >> 5;
        int mt = blockIdx.x & 31;
        int count = expert_count[e];
        m0 = mt * 64;
        if (m0 >= count) return;
        const int* list = expert_list + e * N_TOK;
        if (tid < 64) { int r = m0 + tid; sl[tid] = (r < count) ? list[r] : -1; }
        W2t += (size_t)e * (size_t)D_DIM * F_DIM;
    } else {
        m0 = blockIdx.x * 64;
        if (tid < 64) sl[tid] = m0 + tid;
    }
    int n0 = blockIdx.y * 128;
    __syncthreads();

    int lane = tid & 63, w = tid >> 6;
    int ar = w * 16 + (lane >> 2);
    int aslot = lane & 3;
    int sA = sl[ar];
    int arow = (sA >= 0) ? sA : 0;   // A row = slot (gather) or global row (dense)
    const char* a_src = (const char*)(Abuf + (size_t)arow * K)
                      + ((aslot ^ ((ar >> 2) & 3)) << 4);
    char* a_dst = (char*)As + w * 1024;
    int br0 = w * 32 + (lane >> 2);
    int br1 = br0 + 16;
    int gb0 = (br0 >> 2) & 3, gb1 = (br1 >> 2) & 3;
    const char* b_src0 = (const char*)(W2t + (size_t)(n0 + br0) * K) + ((aslot ^ gb0) << 4);
    const char* b_src1 = (const char*)(W2t + (size_t)(n0 + br1) * K) + ((aslot ^ gb1) << 4);
    char* b_dst0 = (char*)Bs + (w * 2 + 0) * 1024;
    char* b_dst1 = (char*)Bs + (w * 2 + 1) * 1024;

    int wm = w >> 1, wn = w & 1;
    int frow = lane & 15, fkg = lane >> 4;
    int kslot = (fkg ^ ((frow >> 2) & 3)) << 4;

    f32x4 acc[2][4];
#pragma unroll
    for (int i = 0; i < 2; ++i)
#pragma unroll
        for (int j = 0; j < 4; ++j) acc[i][j] = (f32x4)0.f;

    int KB = K * 2;
    for (int kb = 0; kb < KB; kb += 64) {
        async_copy16(a_src + kb, a_dst);
        async_copy16(b_src0 + kb, b_dst0);
        async_copy16(b_src1 + kb, b_dst1);
        __syncthreads();
        bf16x8 af[2], bf[4];
#pragma unroll
        for (int mf = 0; mf < 2; ++mf) {
            int r = wm * 32 + mf * 16 + frow;
            af[mf] = *reinterpret_cast<bf16x8*>((char*)As + r * 64 + kslot);
        }
#pragma unroll
        for (int nf = 0; nf < 4; ++nf) {
            int rb = wn * 64 + nf * 16 + frow;
            bf[nf] = *reinterpret_cast<bf16x8*>((char*)Bs + rb * 64 + kslot);
        }
#pragma unroll
        for (int mf = 0; mf < 2; ++mf)
#pragma unroll
            for (int nf = 0; nf < 4; ++nf)
                acc[mf][nf] = __builtin_amdgcn_mfma_f32_16x16x32_bf16(
                    af[mf], bf[nf], acc[mf][nf], 0, 0, 0);
        __syncthreads();
    }

#pragma unroll
    for (int mf = 0; mf < 2; ++mf) {
#pragma unroll
        for (int j = 0; j < 4; ++j) {
            int rl = wm * 32 + mf * 16 + fkg * 4 + j;
            int s = sl[rl];
            if (s < 0) continue;
            float* op = Out + (size_t)s * D_DIM + n0 + wn * 64 + frow;
#pragma unroll
            for (int nf = 0; nf < 4; ++nf)
                op[nf * 16] = acc[mf][nf][j];
        }
    }
}

// ---------------- combine ----------------
__global__ __launch_bounds__(256) void combine_kernel(
    float* __restrict__ Y, const float* __restrict__ H2,
    const float* __restrict__ assign_w)
{
    int tok = blockIdx.x;
    float w0 = assign_w[2 * tok];
    float w1 = assign_w[2 * tok + 1];
    const float4* h0 = reinterpret_cast<const float4*>(H2 + (size_t)(2 * tok) * D_DIM);
    const float4* h1 = reinterpret_cast<const float4*>(H2 + (size_t)(2 * tok + 1) * D_DIM);
    float4* y = reinterpret_cast<float4*>(Y + (size_t)tok * D_DIM);
#pragma unroll
    for (int i = 0; i < 2; ++i) {
        int idx = threadIdx.x + i * 256;
        float4 yv = y[idx];
        float4 a = h0[idx];
        float4 b = h1[idx];
        yv.x = fmaf(w0, a.x, fmaf(w1, b.x, yv.x));
        yv.y = fmaf(w0, a.y, fmaf(w1, b.y, yv.y));
        yv.z = fmaf(w0, a.z, fmaf(w1, b.z, yv.z));
        yv.w = fmaf(w0, a.w, fmaf(w1, b.w, yv.w));
        y[idx] = yv;
    }
}

// ---------------- fallback path kernels (R3, register-staged fp32) ----------------
#define LDSW 40
template<bool GATHER>
__global__ __launch_bounds__(256) void ffn_in_mfma(
    const float* __restrict__ X, const float* __restrict__ W1,
    const float* __restrict__ W3, short* __restrict__ H, int ldB,
    const int* __restrict__ expert_list, const int* __restrict__ expert_count)
{
    __shared__ short As[64][LDSW];
    __shared__ short Bs1[128][LDSW];
    __shared__ short Bs3[128][LDSW];
    __shared__ int sl[64];
    int tid = threadIdx.x;
    int m0, count;
    const int* list = nullptr;
    if (GATHER) {
        int e = blockIdx.x >> 5; int mt = blockIdx.x & 31;
        count = expert_count[e]; m0 = mt * 64;
        if (m0 >= count) return;
        list = expert_list + e * N_TOK;
        W1 += (size_t)e * D_DIM * F_DIM; W3 += (size_t)e * D_DIM * F_DIM;
    } else { m0 = blockIdx.x * 64; count = N_TOK; }
    int n0 = blockIdx.y * 128;
    if (tid < 64) {
        if (GATHER) { int r = m0 + tid; sl[tid] = (r < count) ? list[r] : -1; }
        else sl[tid] = m0 + tid;
    }
    __syncthreads();
    int arow = tid >> 2, akq = tid & 3;
    int sA = sl[arow];
    bool avalid = sA >= 0;
    int tokrow = avalid ? (GATHER ? (sA >> 1) : sA) : 0;
    const float* Aptr = X + (size_t)tokrow * D_DIM + akq * 8;
    int bnn = (tid & 63) * 2, bkb = (tid >> 6) * 8;
    const float* B1p = W1 + (size_t)bkb * ldB + n0 + bnn;
    const float* B3p = W3 + (size_t)bkb * ldB + n0 + bnn;
    int lane = tid & 63, wv = tid >> 6, wm = wv >> 1, wn = wv & 1;
    int frow = lane & 15, fkg = lane >> 4;
    f32x4 acc1[2][4], acc3[2][4];
#pragma unroll
    for (int i = 0; i < 2; ++i)
#pragma unroll
        for (int j = 0; j < 4; ++j) { acc1[i][j] = (f32x4)0.f; acc3[i][j] = (f32x4)0.f; }
    for (int k0 = 0; k0 < D_DIM; k0 += 32) {
        float4 a0 = make_float4(0,0,0,0), a1 = make_float4(0,0,0,0);
        if (avalid) {
            a0 = *reinterpret_cast<const float4*>(Aptr + k0);
            a1 = *reinterpret_cast<const float4*>(Aptr + k0 + 4);
        }
        float2 b1r[8], b3r[8];
#pragma unroll
        for (int j = 0; j < 8; ++j) {
            b1r[j] = *reinterpret_cast<const float2*>(B1p + (size_t)(k0 + j) * ldB);
            b3r[j] = *reinterpret_cast<const float2*>(B3p + (size_t)(k0 + j) * ldB);
        }
        __syncthreads();
        bf16x8 av;
        av[0]=f2bf(a0.x); av[1]=f2bf(a0.y); av[2]=f2bf(a0.z); av[3]=f2bf(a0.w);
        av[4]=f2bf(a1.x); av[5]=f2bf(a1.y); av[6]=f2bf(a1.z); av[7]=f2bf(a1.w);
        *reinterpret_cast<bf16x8*>(&As[arow][akq * 8]) = av;
        bf16x8 c0, c1, d0, d1;
#pragma unroll
        for (int j = 0; j < 8; ++j) {
            c0[j]=f2bf(b1r[j].x); c1[j]=f2bf(b1r[j].y);
            d0[j]=f2bf(b3r[j].x); d1[j]=f2bf(b3r[j].y);
        }
        *reinterpret_cast<bf16x8*>(&Bs1[bnn][bkb]) = c0;
        *reinterpret_cast<bf16x8*>(&Bs1[bnn + 1][bkb]) = c1;
        *reinterpret_cast<bf16x8*>(&Bs3[bnn][bkb]) = d0;
        *reinterpret_cast<bf16x8*>(&Bs3[bnn + 1][bkb]) = d1;
        __syncthreads();
        bf16x8 af[2], b1f[4], b3f[4];
#pragma unroll
        for (int mf = 0; mf < 2; ++mf)
            af[mf] = *reinterpret_cast<bf16x8*>(&As[wm*32 + mf*16 + frow][fkg*8]);
#pragma unroll
        for (int nf = 0; nf < 4; ++nf) {
            b1f[nf] = *reinterpret_cast<bf16x8*>(&Bs1[wn*64 + nf*16 + frow][fkg*8]);
            b3f[nf] = *reinterpret_cast<bf16x8*>(&Bs3[wn*64 + nf*16 + frow][fkg*8]);
        }
#pragma unroll
        for (int mf = 0; mf < 2; ++mf)
#pragma unroll
            for (int nf = 0; nf < 4; ++nf) {
                acc1[mf][nf] = __builtin_amdgcn_mfma_f32_16x16x32_bf16(af[mf], b1f[nf], acc1[mf][nf], 0,0,0);
                acc3[mf][nf] = __builtin_amdgcn_mfma_f32_16x16x32_bf16(af[mf], b3f[nf], acc3[mf][nf], 0,0,0);
            }
    }
#pragma unroll
    for (int mf = 0; mf < 2; ++mf)
#pragma unroll
        for (int j = 0; j < 4; ++j) {
            int rl = wm*32 + mf*16 + fkg*4 + j;
            int s = sl[rl];
            if (s < 0) continue;
            short* hp = H + (size_t)s * ldB + n0 + wn*64 + frow;
#pragma unroll
            for (int nf = 0; nf < 4; ++nf)
                hp[nf*16] = f2bf(silu1(acc1[mf][nf][j]) * acc3[mf][nf][j]);
        }
}

template<bool GATHER>
__global__ __launch_bounds__(256) void ffn_out_mfma(
    const short* __restrict__ Hbuf, const float* __restrict__ W2,
    float* __restrict__ Out, int ldA, int kmax,
    const int* __restrict__ expert_list, const int* __restrict__ expert_count)
{
    __shared__ short As[64][LDSW];
    __shared__ short Bs[128][LDSW];
    __shared__ int sl[64];
    int tid = threadIdx.x;
    int m0, count;
    const int* list = nullptr;
    if (GATHER) {
        int e = blockIdx.x >> 5; int mt = blockIdx.x & 31;
        count = expert_count[e]; m0 = mt * 64;
        if (m0 >= count) return;
        list = expert_list + e * N_TOK;
        W2 += (size_t)e * F_DIM * D_DIM;
    } else { m0 = blockIdx.x * 64; count = N_TOK; }
    int n0 = blockIdx.y * 128;
    if (tid < 64) {
        if (GATHER) { int r = m0 + tid; sl[tid] = (r < count) ? list[r] : -1; }
        else sl[tid] = m0 + tid;
    }
    __syncthreads();
    int arow = tid >> 2, akq = tid & 3;
    int sA = sl[arow];
    bool avalid = sA >= 0;
    int aIdx = avalid ? sA : 0;
    const short* Aptr = Hbuf + (size_t)aIdx * ldA + akq * 8;
    int bnn = (tid & 63) * 2, bkb = (tid >> 6) * 8;
    const float* B2p = W2 + (size_t)bkb * D_DIM + n0 + bnn;
    int lane = tid & 63, wv = tid >> 6, wm = wv >> 1, wn = wv & 1;
    int frow = lane & 15, fkg = lane >> 4;
    f32x4 acc[2][4];
#pragma unroll
    for (int i = 0; i < 2; ++i)
#pragma unroll
        for (int j = 0; j < 4; ++j) acc[i][j] = (f32x4)0.f;
    for (int k0 = 0; k0 < kmax; k0 += 32) {
        bf16x8 av = (bf16x8)0;
        if (avalid) av = *reinterpret_cast<const bf16x8*>(Aptr + k0);
        float2 br[8];
#pragma unroll
        for (int j = 0; j < 8; ++j)
            br[j] = *reinterpret_cast<const float2*>(B2p + (size_t)(k0 + j) * D_DIM);
        __syncthreads();
        *reinterpret_cast<bf16x8*>(&As[arow][akq * 8]) = av;
        bf16x8 c0, c1;
#pragma unroll
        for (int j = 0; j < 8; ++j) { c0[j]=f2bf(br[j].x); c1[j]=f2bf(br[j].y); }
        *reinterpret_cast<bf16x8*>(&Bs[bnn][bkb]) = c0;
        *reinterpret_cast<bf16x8*>(&Bs[bnn + 1][bkb]) = c1;
        __syncthreads();
        bf16x8 af[2], bf[4];
#pragma unroll
        for (int mf = 0; mf < 2; ++mf)
            af[mf] = *reinterpret_cast<bf16x8*>(&As[wm*32 + mf*16 + frow][fkg*8]);
#pragma unroll
        for (int nf = 0; nf < 4; ++nf)
            bf[nf] = *reinterpret_cast<bf16x8*>(&Bs[wn*64 + nf*16 + frow][fkg*8]);
#pragma unroll
        for (int mf = 0; mf < 2; ++mf)
#pragma unroll
            for (int nf = 0; nf < 4; ++nf)
                acc[mf][nf] = __builtin_amdgcn_mfma_f32_16x16x32_bf16(af[mf], bf[nf], acc[mf][nf], 0,0,0);
    }
#pragma unroll
    for (int mf = 0; mf < 2; ++mf)
#pragma unroll
        for (int j = 0; j < 4; ++j) {
            int rl = wm*32 + mf*16 + fkg*4 + j;
            int s = sl[rl];
            if (s < 0) continue;
            float* op = Out + (size_t)s * D_DIM + n0 + wn*64 + frow;
#pragma unroll
            for (int nf = 0; nf < 4; ++nf)
                op[nf*16] = acc[mf][nf][j];
        }
}

extern "C" void kernel_launch(void* const* d_in, const int* in_sizes, int n_in,
                              void* d_out, int out_size, void* d_ws, size_t ws_size,
                              hipStream_t stream) {
    const float* x   = (const float*)d_in[0];
    const float* gw  = (const float*)d_in[1];
    const float* sw1 = (const float*)d_in[2];
    const float* sw2 = (const float*)d_in[3];
    const float* sw3 = (const float*)d_in[4];
    const float* rw1 = (const float*)d_in[5];
    const float* rw2 = (const float*)d_in[6];
    const float* rw3 = (const float*)d_in[7];
    float* Y = (float*)d_out;

    char* ws = (char*)d_ws;
    float* assign_w     = (float*)(ws);
    int*   expert_count = (int*)(ws + 16384);
    int*   expert_list  = (int*)(ws + 16384 + 256);

    // New-path ws layout
    const size_t XB_OFF   = 131072;
    const size_t SWT1_OFF = XB_OFF + 8388608ull;            //  8.4 MB x_bf
    const size_t SWT3_OFF = SWT1_OFF + 11534336ull;
    const size_t SWT2_OFF = SWT3_OFF + 11534336ull;
    const size_t RWT1_OFF = SWT2_OFF + 11534336ull;
    const size_t RWT3_OFF = RWT1_OFF + 46137344ull;
    const size_t RWT2_OFF = RWT3_OFF + 46137344ull;
    const size_t H_OFF    = RWT2_OFF + 46137344ull;
    const size_t H2_OFF   = H_OFF + 11534336ull;
    const size_t NEED     = H2_OFF + 33554432ull;           // ~216 MB

    zero_counts_kernel<<<1, 64, 0, stream>>>(expert_count);
    gate_kernel<<<N_TOK / 4, 256, 0, stream>>>(x, gw, assign_w, expert_count, expert_list);

    if (ws_size >= NEED) {
        short* Xb   = (short*)(ws + XB_OFF);
        short* swt1 = (short*)(ws + SWT1_OFF);
        short* swt3 = (short*)(ws + SWT3_OFF);
        short* swt2 = (short*)(ws + SWT2_OFF);
        short* rwt1 = (short*)(ws + RWT1_OFF);
        short* rwt3 = (short*)(ws + RWT3_OFF);
        short* rwt2 = (short*)(ws + RWT2_OFF);
        short* H    = (short*)(ws + H_OFF);
        float* H2   = (float*)(ws + H2_OFF);

        cvt_x_kernel<<<(N_TOK * D_DIM / 8) / 256, 256, 0, stream>>>(x, Xb);
        transpose_cvt_kernel<<<dim3(D_DIM/64, FS_DIM/64, 1), 256, 0, stream>>>(sw1, swt1, D_DIM, FS_DIM);
        transpose_cvt_kernel<<<dim3(D_DIM/64, FS_DIM/64, 1), 256, 0, stream>>>(sw3, swt3, D_DIM, FS_DIM);
        transpose_cvt_kernel<<<dim3(FS_DIM/64, D_DIM/64, 1), 256, 0, stream>>>(sw2, swt2, FS_DIM, D_DIM);
        transpose_cvt_kernel<<<dim3(D_DIM/64, F_DIM/64, E_NUM), 256, 0, stream>>>(rw1, rwt1, D_DIM, F_DIM);
        transpose_cvt_kernel<<<dim3(D_DIM/64, F_DIM/64, E_NUM), 256, 0, stream>>>(rw3, rwt3, D_DIM, F_DIM);
        transpose_cvt_kernel<<<dim3(F_DIM/64, D_DIM/64, E_NUM), 256, 0, stream>>>(rw2, rwt2, F_DIM, D_DIM);

        // Shared experts
        ffn_in2<false><<<dim3(N_TOK/64, FS_DIM/128), 256, 0, stream>>>(
            Xb, swt1, swt3, H, FS_DIM, D_DIM, nullptr, nullptr);
        ffn_out2<false><<<dim3(N_TOK/64, D_DIM/128), 256, 0, stream>>>(
            H, swt2, Y, FS_DIM, nullptr, nullptr);
        // Routed experts
        ffn_in2<true><<<dim3(E_NUM*32, F_DIM/128), 256, 0, stream>>>(
            Xb, rwt1, rwt3, H, F_DIM, D_DIM, expert_list, expert_count);
        ffn_out2<true><<<dim3(E_NUM*32, D_DIM/128), 256, 0, stream>>>(
            H, rwt2, H2, F_DIM, expert_list, expert_count);

        combine_kernel<<<N_TOK, 256, 0, stream>>>(Y, H2, assign_w);
    } else {
        // Fallback: R3 register-staged path (ws ~45 MB)
        short* H  = (short*)(ws + 131072);
        float* H2 = (float*)(ws + 131072 + 11534336);

        ffn_in_mfma<false><<<dim3(N_TOK/64, FS_DIM/128), 256, 0, stream>>>(
            x, sw1, sw3, H, FS_DIM, nullptr, nullptr);
        ffn_out_mfma<false><<<dim3(N_TOK/64, D_DIM/128), 256, 0, stream>>>(
            H, sw2, Y, FS_DIM, FS_DIM, nullptr, nullptr);
        ffn_in_mfma<true><<<dim3(E_NUM*32, F_DIM/128), 256, 0, stream>>>(
            x, rw1, rw3, H, F_DIM, expert_list, expert_count);
        ffn_out_mfma<true><<<dim3(E_NUM*32, D_DIM/128), 256, 0, stream>>>(
            H, rw2, H2, F_DIM, F_DIM, expert_list, expert_count);
        combine_kernel<<<N_TOK, 256, 0, stream>>>(Y, H2, assign_w);
    }
}

// Round 6
// 490.003 us; speedup vs baseline: 2.2681x; 1.5899x over previous
//
#include <hip/hip_runtime.h>
#include <hip/hip_bf16.h>
#include <math.h>

#define D_DIM 2048
#define F_DIM 1408
#define FS_DIM 2816
#define E_NUM 8
#define N_TOK 2048

typedef __attribute__((ext_vector_type(8))) short bf16x8;
typedef __attribute__((ext_vector_type(4))) float f32x4;

__device__ inline short f2bf(float f) {
    __hip_bfloat16 h = __float2bfloat16(f);
    return *reinterpret_cast<short*>(&h);
}
__device__ inline float silu1(float v) { return v / (1.f + expf(-v)); }

__device__ inline void async_copy16(const void* g, void* l) {
    __builtin_amdgcn_global_load_lds(
        (const __attribute__((address_space(1))) void*)g,
        (__attribute__((address_space(3))) void*)l, 16, 0, 0);
}

__global__ __launch_bounds__(64) void zero_counts_kernel(int* c) {
    if (threadIdx.x < E_NUM) c[threadIdx.x] = 0;
}

// ---------------- gate ----------------
__global__ __launch_bounds__(256) void gate_kernel(
    const float* __restrict__ x, const float* __restrict__ gw,
    float* __restrict__ assign_w, int* __restrict__ expert_count,
    int* __restrict__ expert_list)
{
    int wid = (blockIdx.x * 256 + threadIdx.x) >> 6;
    int lane = threadIdx.x & 63;
    if (wid >= N_TOK) return;
    const float* xr = x + (size_t)wid * D_DIM;
    float p[E_NUM];
#pragma unroll
    for (int e = 0; e < E_NUM; ++e) p[e] = 0.f;
    for (int d = lane; d < D_DIM; d += 64) {
        float xv = xr[d];
        const float4* g = reinterpret_cast<const float4*>(gw + (size_t)d * E_NUM);
        float4 g0 = g[0], g1 = g[1];
        p[0] = fmaf(xv, g0.x, p[0]); p[1] = fmaf(xv, g0.y, p[1]);
        p[2] = fmaf(xv, g0.z, p[2]); p[3] = fmaf(xv, g0.w, p[3]);
        p[4] = fmaf(xv, g1.x, p[4]); p[5] = fmaf(xv, g1.y, p[5]);
        p[6] = fmaf(xv, g1.z, p[6]); p[7] = fmaf(xv, g1.w, p[7]);
    }
#pragma unroll
    for (int off = 32; off > 0; off >>= 1)
#pragma unroll
        for (int e = 0; e < E_NUM; ++e)
            p[e] += __shfl_xor(p[e], off, 64);
    if (lane == 0) {
        float m = p[0];
#pragma unroll
        for (int e = 1; e < E_NUM; ++e) m = fmaxf(m, p[e]);
        float s = 0.f, pr[E_NUM];
#pragma unroll
        for (int e = 0; e < E_NUM; ++e) { pr[e] = expf(p[e] - m); s += pr[e]; }
        float inv = 1.f / s;
#pragma unroll
        for (int e = 0; e < E_NUM; ++e) pr[e] *= inv;
        int i0 = 0;
#pragma unroll
        for (int e = 1; e < E_NUM; ++e) if (pr[e] > pr[i0]) i0 = e;
        int i1 = (i0 == 0) ? 1 : 0;
#pragma unroll
        for (int e = 0; e < E_NUM; ++e) if (e != i0 && pr[e] > pr[i1]) i1 = e;
        int s0 = wid * 2, s1 = wid * 2 + 1;
        assign_w[s0] = pr[i0];
        assign_w[s1] = pr[i1];
        int p0 = atomicAdd(&expert_count[i0], 1);
        expert_list[i0 * N_TOK + p0] = s0;
        int p1 = atomicAdd(&expert_count[i1], 1);
        expert_list[i1 * N_TOK + p1] = s1;
    }
}

// ---------------- converts ----------------
__global__ __launch_bounds__(256) void cvt_x_kernel(
    const float* __restrict__ in, short* __restrict__ out)
{
    int i = (blockIdx.x * 256 + threadIdx.x) * 8;
    float4 v0 = *reinterpret_cast<const float4*>(in + i);
    float4 v1 = *reinterpret_cast<const float4*>(in + i + 4);
    bf16x8 o;
    o[0] = f2bf(v0.x); o[1] = f2bf(v0.y); o[2] = f2bf(v0.z); o[3] = f2bf(v0.w);
    o[4] = f2bf(v1.x); o[5] = f2bf(v1.y); o[6] = f2bf(v1.z); o[7] = f2bf(v1.w);
    *reinterpret_cast<bf16x8*>(out + i) = o;
}

// out[b][n][k] = bf16(in[b][k][n])
__global__ __launch_bounds__(256) void transpose_cvt_kernel(
    const float* __restrict__ in, short* __restrict__ out, int K, int N)
{
    __shared__ float tile[64][65];
    int b = blockIdx.z;
    in  += (size_t)b * K * N;
    out += (size_t)b * N * K;
    int k0 = blockIdx.x * 64;
    int n0 = blockIdx.y * 64;
    int t = threadIdx.x;
    int tr = t >> 4;
    int tc4 = (t & 15) * 4;
#pragma unroll
    for (int i = 0; i < 4; ++i) {
        int r = tr + i * 16;
        float4 v = *reinterpret_cast<const float4*>(in + (size_t)(k0 + r) * N + n0 + tc4);
        tile[r][tc4 + 0] = v.x; tile[r][tc4 + 1] = v.y;
        tile[r][tc4 + 2] = v.z; tile[r][tc4 + 3] = v.w;
    }
    __syncthreads();
#pragma unroll
    for (int i = 0; i < 4; ++i) {
        int n = tr + i * 16;
        short4 s4;
        s4.x = f2bf(tile[tc4 + 0][n]);
        s4.y = f2bf(tile[tc4 + 1][n]);
        s4.z = f2bf(tile[tc4 + 2][n]);
        s4.w = f2bf(tile[tc4 + 3][n]);
        *reinterpret_cast<short4*>(out + (size_t)(n0 + n) * K + k0 + tc4) = s4;
    }
}

// ---------------- GEMMs: 64x128 tile, BK=64, double-buffer + prefetch ----------------
// 1D grid, XCD-group scheduling: group g = (e, nt); all 32 m-tiles of a group
// run on XCD g%8 so the weight panel stays in that XCD's L2.
// LDS rows = 128B; swizzle: 16B-slot q stored at slot q^(row&7), same XOR on
// the pre-swizzled global source (involution both sides).

template<bool GATHER>
__global__ __launch_bounds__(256) void ffn_in3(
    const short* __restrict__ Xb,    // bf16 [*, K]
    const short* __restrict__ W1t,   // bf16 [N][K] (+ e*F*D for GATHER)
    const short* __restrict__ W3t,
    short* __restrict__ H,           // bf16 [row][ldH]
    int ldH, int K, int NT, int NGROUP,
    const int* __restrict__ expert_list,
    const int* __restrict__ expert_count)
{
    __shared__ short As[2][64 * 64];    // 8KB per buf
    __shared__ short Bs1[2][128 * 64];  // 16KB per buf
    __shared__ short Bs3[2][128 * 64];

    int bid = blockIdx.x;
    int xcd = bid & 7, qq = bid >> 3;
    int mtile = qq & 31, gq = qq >> 5;
    int g = gq * 8 + xcd;
    if (g >= NGROUP) return;
    int e = g / NT, nt = g - e * NT;
    int m0 = mtile * 64, n0 = nt * 128;
    int count = 0;
    const int* list = nullptr;
    if (GATHER) {
        count = expert_count[e];
        if (m0 >= count) return;
        list = expert_list + e * N_TOK;
        W1t += (size_t)e * F_DIM * D_DIM;
        W3t += (size_t)e * F_DIM * D_DIM;
    }

    int tid = threadIdx.x;
    int l = tid & 63, w = tid >> 6;
    int Kb = K * 2;

    const char* aS[2];
#pragma unroll
    for (int j = 0; j < 2; ++j) {
        int c = w * 2 + j;
        int r = c * 8 + (l >> 3);
        int tok;
        if (GATHER) { int rr = m0 + r; tok = (rr < count) ? (list[rr] >> 1) : 0; }
        else tok = m0 + r;
        aS[j] = (const char*)Xb + (size_t)tok * Kb + (((l & 7) ^ (r & 7)) << 4);
    }
    const char* b1S[4]; const char* b3S[4];
#pragma unroll
    for (int j = 0; j < 4; ++j) {
        int c = w * 4 + j;
        int r = c * 8 + (l >> 3);
        size_t off = (size_t)(n0 + r) * Kb + (((l & 7) ^ (r & 7)) << 4);
        b1S[j] = (const char*)W1t + off;
        b3S[j] = (const char*)W3t + off;
    }

    auto STAGE = [&](int buf, int kb) {
#pragma unroll
        for (int j = 0; j < 2; ++j)
            async_copy16(aS[j] + kb, (char*)(&As[buf][0]) + (w * 2 + j) * 1024);
#pragma unroll
        for (int j = 0; j < 4; ++j) {
            async_copy16(b1S[j] + kb, (char*)(&Bs1[buf][0]) + (w * 4 + j) * 1024);
            async_copy16(b3S[j] + kb, (char*)(&Bs3[buf][0]) + (w * 4 + j) * 1024);
        }
    };

    int wm = w >> 1, wn = w & 1;
    int frow = l & 15, fkg = l >> 4;

    f32x4 acc1[2][4], acc3[2][4];
#pragma unroll
    for (int i = 0; i < 2; ++i)
#pragma unroll
        for (int j = 0; j < 4; ++j) { acc1[i][j] = (f32x4)0.f; acc3[i][j] = (f32x4)0.f; }

    int NIT = Kb >> 7;                  // BK=64 -> 128 bytes/row/iter
    STAGE(0, 0);
    __syncthreads();
    int buf = 0;
    for (int it = 0; it < NIT; ++it) {
        if (it + 1 < NIT) STAGE(buf ^ 1, (it + 1) << 7);
#pragma unroll
        for (int kk = 0; kk < 2; ++kk) {
            bf16x8 af[2], b1f[4], b3f[4];
#pragma unroll
            for (int mf = 0; mf < 2; ++mf) {
                int r = wm * 32 + mf * 16 + frow;
                af[mf] = *reinterpret_cast<const bf16x8*>(
                    (const char*)(&As[buf][0]) + r * 128 + ((((kk << 2) | fkg) ^ (r & 7)) << 4));
            }
#pragma unroll
            for (int nf = 0; nf < 4; ++nf) {
                int r = wn * 64 + nf * 16 + frow;
                int so = (((kk << 2) | fkg) ^ (r & 7)) << 4;
                b1f[nf] = *reinterpret_cast<const bf16x8*>((const char*)(&Bs1[buf][0]) + r * 128 + so);
                b3f[nf] = *reinterpret_cast<const bf16x8*>((const char*)(&Bs3[buf][0]) + r * 128 + so);
            }
#pragma unroll
            for (int mf = 0; mf < 2; ++mf)
#pragma unroll
                for (int nf = 0; nf < 4; ++nf) {
                    acc1[mf][nf] = __builtin_amdgcn_mfma_f32_16x16x32_bf16(
                        af[mf], b1f[nf], acc1[mf][nf], 0, 0, 0);
                    acc3[mf][nf] = __builtin_amdgcn_mfma_f32_16x16x32_bf16(
                        af[mf], b3f[nf], acc3[mf][nf], 0, 0, 0);
                }
        }
        __syncthreads();
        buf ^= 1;
    }

#pragma unroll
    for (int mf = 0; mf < 2; ++mf) {
#pragma unroll
        for (int jj = 0; jj < 4; ++jj) {
            int rl = wm * 32 + mf * 16 + fkg * 4 + jj;
            int s;
            if (GATHER) { int rr = m0 + rl; if (rr >= count) continue; s = list[rr]; }
            else s = m0 + rl;
            short* hp = H + (size_t)s * ldH + n0 + wn * 64 + frow;
#pragma unroll
            for (int nf = 0; nf < 4; ++nf)
                hp[nf * 16] = f2bf(silu1(acc1[mf][nf][jj]) * acc3[mf][nf][jj]);
        }
    }
}

template<bool GATHER>
__global__ __launch_bounds__(256) void ffn_out3(
    const short* __restrict__ Abuf,  // bf16 [row][K]
    const short* __restrict__ W2t,   // bf16 [D][K] (+ e*D*F for GATHER)
    float* __restrict__ Out,         // fp32 [row][D_DIM]
    int K, int NT, int NGROUP,
    const int* __restrict__ expert_list,
    const int* __restrict__ expert_count)
{
    __shared__ short As[2][64 * 64];
    __shared__ short Bs[2][128 * 64];

    int bid = blockIdx.x;
    int xcd = bid & 7, qq = bid >> 3;
    int mtile = qq & 31, gq = qq >> 5;
    int g = gq * 8 + xcd;
    if (g >= NGROUP) return;
    int e = g / NT, nt = g - e * NT;
    int m0 = mtile * 64, n0 = nt * 128;
    int count = 0;
    const int* list = nullptr;
    if (GATHER) {
        count = expert_count[e];
        if (m0 >= count) return;
        list = expert_list + e * N_TOK;
        W2t += (size_t)e * (size_t)D_DIM * F_DIM;
    }

    int tid = threadIdx.x;
    int l = tid & 63, w = tid >> 6;
    int Kb = K * 2;

    const char* aS[2];
#pragma unroll
    for (int j = 0; j < 2; ++j) {
        int c = w * 2 + j;
        int r = c * 8 + (l >> 3);
        int arow;
        if (GATHER) { int rr = m0 + r; arow = (rr < count) ? list[rr] : 0; }
        else arow = m0 + r;
        aS[j] = (const char*)Abuf + (size_t)arow * Kb + (((l & 7) ^ (r & 7)) << 4);
    }
    const char* bS[4];
#pragma unroll
    for (int j = 0; j < 4; ++j) {
        int c = w * 4 + j;
        int r = c * 8 + (l >> 3);
        bS[j] = (const char*)W2t + (size_t)(n0 + r) * Kb + (((l & 7) ^ (r & 7)) << 4);
    }

    auto STAGE = [&](int buf, int kb) {
#pragma unroll
        for (int j = 0; j < 2; ++j)
            async_copy16(aS[j] + kb, (char*)(&As[buf][0]) + (w * 2 + j) * 1024);
#pragma unroll
        for (int j = 0; j < 4; ++j)
            async_copy16(bS[j] + kb, (char*)(&Bs[buf][0]) + (w * 4 + j) * 1024);
    };

    int wm = w >> 1, wn = w & 1;
    int frow = l & 15, fkg = l >> 4;

    f32x4 acc[2][4];
#pragma unroll
    for (int i = 0; i < 2; ++i)
#pragma unroll
        for (int j = 0; j < 4; ++j) acc[i][j] = (f32x4)0.f;

    int NIT = Kb >> 7;
    STAGE(0, 0);
    __syncthreads();
    int buf = 0;
    for (int it = 0; it < NIT; ++it) {
        if (it + 1 < NIT) STAGE(buf ^ 1, (it + 1) << 7);
#pragma unroll
        for (int kk = 0; kk < 2; ++kk) {
            bf16x8 af[2], bf[4];
#pragma unroll
            for (int mf = 0; mf < 2; ++mf) {
                int r = wm * 32 + mf * 16 + frow;
                af[mf] = *reinterpret_cast<const bf16x8*>(
                    (const char*)(&As[buf][0]) + r * 128 + ((((kk << 2) | fkg) ^ (r & 7)) << 4));
            }
#pragma unroll
            for (int nf = 0; nf < 4; ++nf) {
                int r = wn * 64 + nf * 16 + frow;
                bf[nf] = *reinterpret_cast<const bf16x8*>(
                    (const char*)(&Bs[buf][0]) + r * 128 + ((((kk << 2) | fkg) ^ (r & 7)) << 4));
            }
#pragma unroll
            for (int mf = 0; mf < 2; ++mf)
#pragma unroll
                for (int nf = 0; nf < 4; ++nf)
                    acc[mf][nf] = __builtin_amdgcn_mfma_f32_16x16x32_bf16(
                        af[mf], bf[nf], acc[mf][nf], 0, 0, 0);
        }
        __syncthreads();
        buf ^= 1;
    }

#pragma unroll
    for (int mf = 0; mf < 2; ++mf) {
#pragma unroll
        for (int jj = 0; jj < 4; ++jj) {
            int rl = wm * 32 + mf * 16 + fkg * 4 + jj;
            int s;
            if (GATHER) { int rr = m0 + rl; if (rr >= count) continue; s = list[rr]; }
            else s = m0 + rl;
            float* op = Out + (size_t)s * D_DIM + n0 + wn * 64 + frow;
#pragma unroll
            for (int nf = 0; nf < 4; ++nf)
                op[nf * 16] = acc[mf][nf][jj];
        }
    }
}

// ---------------- combine ----------------
__global__ __launch_bounds__(256) void combine_kernel(
    float* __restrict__ Y, const float* __restrict__ H2,
    const float* __restrict__ assign_w)
{
    int tok = blockIdx.x;
    float w0 = assign_w[2 * tok];
    float w1 = assign_w[2 * tok + 1];
    const float4* h0 = reinterpret_cast<const float4*>(H2 + (size_t)(2 * tok) * D_DIM);
    const float4* h1 = reinterpret_cast<const float4*>(H2 + (size_t)(2 * tok + 1) * D_DIM);
    float4* y = reinterpret_cast<float4*>(Y + (size_t)tok * D_DIM);
#pragma unroll
    for (int i = 0; i < 2; ++i) {
        int idx = threadIdx.x + i * 256;
        float4 yv = y[idx];
        float4 a = h0[idx];
        float4 b = h1[idx];
        yv.x = fmaf(w0, a.x, fmaf(w1, b.x, yv.x));
        yv.y = fmaf(w0, a.y, fmaf(w1, b.y, yv.y));
        yv.z = fmaf(w0, a.z, fmaf(w1, b.z, yv.z));
        yv.w = fmaf(w0, a.w, fmaf(w1, b.w, yv.w));
        y[idx] = yv;
    }
}

extern "C" void kernel_launch(void* const* d_in, const int* in_sizes, int n_in,
                              void* d_out, int out_size, void* d_ws, size_t ws_size,
                              hipStream_t stream) {
    const float* x   = (const float*)d_in[0];
    const float* gw  = (const float*)d_in[1];
    const float* sw1 = (const float*)d_in[2];
    const float* sw2 = (const float*)d_in[3];
    const float* sw3 = (const float*)d_in[4];
    const float* rw1 = (const float*)d_in[5];
    const float* rw2 = (const float*)d_in[6];
    const float* rw3 = (const float*)d_in[7];
    float* Y = (float*)d_out;

    char* ws = (char*)d_ws;
    float* assign_w     = (float*)(ws);
    int*   expert_count = (int*)(ws + 16384);
    int*   expert_list  = (int*)(ws + 16384 + 256);

    const size_t XB_OFF   = 131072;
    const size_t SWT1_OFF = XB_OFF + 8388608ull;
    const size_t SWT3_OFF = SWT1_OFF + 11534336ull;
    const size_t SWT2_OFF = SWT3_OFF + 11534336ull;
    const size_t RWT1_OFF = SWT2_OFF + 11534336ull;
    const size_t RWT3_OFF = RWT1_OFF + 46137344ull;
    const size_t RWT2_OFF = RWT3_OFF + 46137344ull;
    const size_t H_OFF    = RWT2_OFF + 46137344ull;
    const size_t H2_OFF   = H_OFF + 11534336ull;

    short* Xb   = (short*)(ws + XB_OFF);
    short* swt1 = (short*)(ws + SWT1_OFF);
    short* swt3 = (short*)(ws + SWT3_OFF);
    short* swt2 = (short*)(ws + SWT2_OFF);
    short* rwt1 = (short*)(ws + RWT1_OFF);
    short* rwt3 = (short*)(ws + RWT3_OFF);
    short* rwt2 = (short*)(ws + RWT2_OFF);
    short* H    = (short*)(ws + H_OFF);
    float* H2   = (float*)(ws + H2_OFF);

    zero_counts_kernel<<<1, 64, 0, stream>>>(expert_count);
    gate_kernel<<<N_TOK / 4, 256, 0, stream>>>(x, gw, assign_w, expert_count, expert_list);

    cvt_x_kernel<<<(N_TOK * D_DIM / 8) / 256, 256, 0, stream>>>(x, Xb);
    transpose_cvt_kernel<<<dim3(D_DIM/64, FS_DIM/64, 1), 256, 0, stream>>>(sw1, swt1, D_DIM, FS_DIM);
    transpose_cvt_kernel<<<dim3(D_DIM/64, FS_DIM/64, 1), 256, 0, stream>>>(sw3, swt3, D_DIM, FS_DIM);
    transpose_cvt_kernel<<<dim3(FS_DIM/64, D_DIM/64, 1), 256, 0, stream>>>(sw2, swt2, FS_DIM, D_DIM);
    transpose_cvt_kernel<<<dim3(D_DIM/64, F_DIM/64, E_NUM), 256, 0, stream>>>(rw1, rwt1, D_DIM, F_DIM);
    transpose_cvt_kernel<<<dim3(D_DIM/64, F_DIM/64, E_NUM), 256, 0, stream>>>(rw3, rwt3, D_DIM, F_DIM);
    transpose_cvt_kernel<<<dim3(F_DIM/64, D_DIM/64, E_NUM), 256, 0, stream>>>(rw2, rwt2, F_DIM, D_DIM);

    auto gridFor = [](int G) { return ((G + 7) / 8) * 8 * 32; };

    // Shared experts: NT=22 groups (N=2816/128), NGROUP=22
    ffn_in3<false><<<gridFor(22), 256, 0, stream>>>(
        Xb, swt1, swt3, H, FS_DIM, D_DIM, 22, 22, nullptr, nullptr);
    // Shared out: K=FS_DIM, NT=16, NGROUP=16
    ffn_out3<false><<<gridFor(16), 256, 0, stream>>>(
        H, swt2, Y, FS_DIM, 16, 16, nullptr, nullptr);

    // Routed in: NT=11 (1408/128), NGROUP=8*11=88
    ffn_in3<true><<<gridFor(88), 256, 0, stream>>>(
        Xb, rwt1, rwt3, H, F_DIM, D_DIM, 11, 88, expert_list, expert_count);
    // Routed out: K=F_DIM, NT=16, NGROUP=8*16=128
    ffn_out3<true><<<gridFor(128), 256, 0, stream>>>(
        H, rwt2, H2, F_DIM, 16, 128, expert_list, expert_count);

    combine_kernel<<<N_TOK, 256, 0, stream>>>(Y, H2, assign_w);
}

// Round 7
// 358.257 us; speedup vs baseline: 3.1021x; 1.3677x over previous
//
#include <hip/hip_runtime.h>
#include <hip/hip_bf16.h>
#include <math.h>

#define D_DIM 2048
#define F_DIM 1408
#define FS_DIM 2816
#define E_NUM 8
#define N_TOK 2048

typedef __attribute__((ext_vector_type(8))) short bf16x8;
typedef __attribute__((ext_vector_type(4))) float f32x4;

__device__ inline short f2bf(float f) {
    __hip_bfloat16 h = __float2bfloat16(f);
    return *reinterpret_cast<short*>(&h);
}
__device__ inline float bf2f(short s) {
    __hip_bfloat16 h; *reinterpret_cast<short*>(&h) = s;
    return __bfloat162float(h);
}
__device__ inline float silu1(float v) { return v / (1.f + expf(-v)); }

__device__ inline void async_copy16(const void* g, void* l) {
    __builtin_amdgcn_global_load_lds(
        (const __attribute__((address_space(1))) void*)g,
        (__attribute__((address_space(3))) void*)l, 16, 0, 0);
}

// 64x64 transpose+convert tile: out[n][k] = bf16(in[k][n])
__device__ inline void t64(const float* in, short* out, int K, int N,
                           int kt, int nt, float (*tile)[65])
{
    int k0 = kt * 64, n0 = nt * 64;
    int t = threadIdx.x, tr = t >> 4, tc4 = (t & 15) * 4;
#pragma unroll
    for (int i = 0; i < 4; ++i) {
        int r = tr + i * 16;
        float4 v = *reinterpret_cast<const float4*>(in + (size_t)(k0 + r) * N + n0 + tc4);
        tile[r][tc4 + 0] = v.x; tile[r][tc4 + 1] = v.y;
        tile[r][tc4 + 2] = v.z; tile[r][tc4 + 3] = v.w;
    }
    __syncthreads();
#pragma unroll
    for (int i = 0; i < 4; ++i) {
        int n = tr + i * 16;
        short4 s4;
        s4.x = f2bf(tile[tc4 + 0][n]);
        s4.y = f2bf(tile[tc4 + 1][n]);
        s4.z = f2bf(tile[tc4 + 2][n]);
        s4.w = f2bf(tile[tc4 + 3][n]);
        *reinterpret_cast<short4*>(out + (size_t)(n0 + n) * K + k0 + tc4) = s4;
    }
}

// ---------------- prep: gate | cvt_x | transpose(sw1,sw3,rw1,rw3) ----------------
__global__ __launch_bounds__(256) void prep_kernel(
    const float* __restrict__ x, const float* __restrict__ gw,
    float* __restrict__ assign_w, int* __restrict__ expert_count,
    int* __restrict__ expert_list, short* __restrict__ Xb,
    const float* __restrict__ sw1, short* __restrict__ swt1,
    const float* __restrict__ sw3, short* __restrict__ swt3,
    const float* __restrict__ rw1, short* __restrict__ rwt1,
    const float* __restrict__ rw3, short* __restrict__ rwt3)
{
    __shared__ float tile[64][65];
    int bid = blockIdx.x;
    int tid = threadIdx.x;
    if (bid < 512) {
        // gate: 4 tokens per block, 1 wave each
        int wid = bid * 4 + (tid >> 6);
        int lane = tid & 63;
        const float* xr = x + (size_t)wid * D_DIM;
        float p[E_NUM];
#pragma unroll
        for (int e = 0; e < E_NUM; ++e) p[e] = 0.f;
        for (int d = lane; d < D_DIM; d += 64) {
            float xv = xr[d];
            const float4* g = reinterpret_cast<const float4*>(gw + (size_t)d * E_NUM);
            float4 g0 = g[0], g1 = g[1];
            p[0] = fmaf(xv, g0.x, p[0]); p[1] = fmaf(xv, g0.y, p[1]);
            p[2] = fmaf(xv, g0.z, p[2]); p[3] = fmaf(xv, g0.w, p[3]);
            p[4] = fmaf(xv, g1.x, p[4]); p[5] = fmaf(xv, g1.y, p[5]);
            p[6] = fmaf(xv, g1.z, p[6]); p[7] = fmaf(xv, g1.w, p[7]);
        }
#pragma unroll
        for (int off = 32; off > 0; off >>= 1)
#pragma unroll
            for (int e = 0; e < E_NUM; ++e)
                p[e] += __shfl_xor(p[e], off, 64);
        if (lane == 0) {
            float m = p[0];
#pragma unroll
            for (int e = 1; e < E_NUM; ++e) m = fmaxf(m, p[e]);
            float s = 0.f, pr[E_NUM];
#pragma unroll
            for (int e = 0; e < E_NUM; ++e) { pr[e] = expf(p[e] - m); s += pr[e]; }
            float inv = 1.f / s;
#pragma unroll
            for (int e = 0; e < E_NUM; ++e) pr[e] *= inv;
            int i0 = 0;
#pragma unroll
            for (int e = 1; e < E_NUM; ++e) if (pr[e] > pr[i0]) i0 = e;
            int i1 = (i0 == 0) ? 1 : 0;
#pragma unroll
            for (int e = 0; e < E_NUM; ++e) if (e != i0 && pr[e] > pr[i1]) i1 = e;
            int s0 = wid * 2, s1 = wid * 2 + 1;
            assign_w[s0] = pr[i0];
            assign_w[s1] = pr[i1];
            int p0 = atomicAdd(&expert_count[i0], 1);
            expert_list[i0 * N_TOK + p0] = s0;
            int p1 = atomicAdd(&expert_count[i1], 1);
            expert_list[i1 * N_TOK + p1] = s1;
        }
    } else if (bid < 2560) {
        // cvt_x
        int i = ((bid - 512) * 256 + tid) * 8;
        float4 v0 = *reinterpret_cast<const float4*>(x + i);
        float4 v1 = *reinterpret_cast<const float4*>(x + i + 4);
        bf16x8 o;
        o[0] = f2bf(v0.x); o[1] = f2bf(v0.y); o[2] = f2bf(v0.z); o[3] = f2bf(v0.w);
        o[4] = f2bf(v1.x); o[5] = f2bf(v1.y); o[6] = f2bf(v1.z); o[7] = f2bf(v1.w);
        *reinterpret_cast<bf16x8*>(Xb + i) = o;
    } else if (bid < 3968) {
        int t = bid - 2560;   // sw1: K=2048(32 tiles), N=2816(44)
        t64(sw1, swt1, D_DIM, FS_DIM, t % 32, t / 32, tile);
    } else if (bid < 5376) {
        int t = bid - 3968;
        t64(sw3, swt3, D_DIM, FS_DIM, t % 32, t / 32, tile);
    } else if (bid < 11008) {
        int t = bid - 5376;   // rw1: per-e K=2048(32) N=1408(22)
        int e = t / 704, r = t % 704;
        t64(rw1 + (size_t)e * D_DIM * F_DIM, rwt1 + (size_t)e * F_DIM * D_DIM,
            D_DIM, F_DIM, r % 32, r / 32, tile);
    } else {
        int t = bid - 11008;
        int e = t / 704, r = t % 704;
        t64(rw3 + (size_t)e * D_DIM * F_DIM, rwt3 + (size_t)e * F_DIM * D_DIM,
            D_DIM, F_DIM, r % 32, r / 32, tile);
    }
}

// ---------------- fused in-GEMM (shared + routed) + w2 transposes ----------------
// GEMM: BM=128, BN=64, BK=64, 4 waves (wave-tile 64x32, mf=4 nf=2),
// single-buffered LDS (32KB), 2 barriers/iter; XCD-group scheduling;
// 128B rows, swizzle slot q -> q^(row&7) on both source and ds_read.
__global__ __launch_bounds__(256) void moe_in_kernel(
    const short* __restrict__ Xb,
    const short* __restrict__ swt1, const short* __restrict__ swt3, short* __restrict__ Hs,
    const short* __restrict__ rwt1, const short* __restrict__ rwt3, short* __restrict__ Hr,
    const int* __restrict__ expert_list, const int* __restrict__ expert_count,
    const float* __restrict__ sw2, short* __restrict__ swt2,
    const float* __restrict__ rw2, short* __restrict__ rwt2)
{
    __shared__ char SMEM[32768];
    __shared__ int sl[128];
    int bid = blockIdx.x;
    int tid = threadIdx.x;

    if (bid >= 3584) {
        // appended transpose blocks (independent of this dispatch's GEMM work)
        int t = bid - 3584;
        float (*tile)[65] = reinterpret_cast<float (*)[65]>(SMEM);
        if (t < 1408) {
            t64(sw2, swt2, FS_DIM, D_DIM, t % 44, t / 44, tile);
        } else {
            t -= 1408;
            int e = t / 704, r = t % 704;
            t64(rw2 + (size_t)e * F_DIM * D_DIM, rwt2 + (size_t)e * D_DIM * F_DIM,
                F_DIM, D_DIM, r % 22, r / 22, tile);
        }
        return;
    }

    int xcd = bid & 7, qq = bid >> 3, mtile = qq & 15, gq = qq >> 4;
    int g = gq * 8 + xcd;
    if (g >= 220) return;
    const short *W1, *W3;
    short* H;
    int ldH, n0, count;
    bool gather;
    const int* list = nullptr;
    int m0 = mtile * 128;
    if (g < 44) {
        gather = false; count = N_TOK;
        W1 = swt1; W3 = swt3; H = Hs; ldH = FS_DIM; n0 = g * 64;
    } else {
        int g2 = g - 44, e = g2 / 22;
        n0 = (g2 % 22) * 64;
        gather = true;
        count = expert_count[e];
        if (m0 >= count) return;
        list = expert_list + e * N_TOK;
        W1 = rwt1 + (size_t)e * F_DIM * D_DIM;
        W3 = rwt3 + (size_t)e * F_DIM * D_DIM;
        H = Hr; ldH = F_DIM;
    }
    if (tid < 128) {
        int rr = m0 + tid;
        sl[tid] = gather ? ((rr < count) ? list[rr] : -1) : rr;
    }
    __syncthreads();

    int l = tid & 63, w = tid >> 6;
    char* As  = SMEM;            // 128 x 128B = 16K
    char* B1s = SMEM + 16384;    // 64 x 128B = 8K
    char* B3s = SMEM + 24576;    // 8K

    const char* aS[4];
#pragma unroll
    for (int j = 0; j < 4; ++j) {
        int r = (w * 4 + j) * 8 + (l >> 3);
        int s = sl[r];
        int tok = gather ? (s >= 0 ? (s >> 1) : 0) : s;
        aS[j] = (const char*)Xb + (size_t)tok * 4096 + (((l & 7) ^ (r & 7)) << 4);
    }
    const char* b1S[2]; const char* b3S[2];
#pragma unroll
    for (int j = 0; j < 2; ++j) {
        int r = (w * 2 + j) * 8 + (l >> 3);
        size_t off = (size_t)(n0 + r) * 4096 + (((l & 7) ^ (r & 7)) << 4);
        b1S[j] = (const char*)W1 + off;
        b3S[j] = (const char*)W3 + off;
    }

    int wm = w >> 1, wn = w & 1, frow = l & 15, fkg = l >> 4;
    f32x4 acc1[4][2], acc3[4][2];
#pragma unroll
    for (int i = 0; i < 4; ++i)
#pragma unroll
        for (int j = 0; j < 2; ++j) { acc1[i][j] = (f32x4)0.f; acc3[i][j] = (f32x4)0.f; }

    for (int it = 0; it < 32; ++it) {
        int kb = it << 7;
#pragma unroll
        for (int j = 0; j < 4; ++j)
            async_copy16(aS[j] + kb, As + (w * 4 + j) * 1024);
#pragma unroll
        for (int j = 0; j < 2; ++j) {
            async_copy16(b1S[j] + kb, B1s + (w * 2 + j) * 1024);
            async_copy16(b3S[j] + kb, B3s + (w * 2 + j) * 1024);
        }
        __syncthreads();
#pragma unroll
        for (int kk = 0; kk < 2; ++kk) {
            bf16x8 af[4], b1f[2], b3f[2];
#pragma unroll
            for (int mf = 0; mf < 4; ++mf) {
                int r = wm * 64 + mf * 16 + frow;
                af[mf] = *reinterpret_cast<const bf16x8*>(
                    As + r * 128 + ((((kk << 2) | fkg) ^ (r & 7)) << 4));
            }
#pragma unroll
            for (int nf = 0; nf < 2; ++nf) {
                int r = wn * 32 + nf * 16 + frow;
                int so = (((kk << 2) | fkg) ^ (r & 7)) << 4;
                b1f[nf] = *reinterpret_cast<const bf16x8*>(B1s + r * 128 + so);
                b3f[nf] = *reinterpret_cast<const bf16x8*>(B3s + r * 128 + so);
            }
#pragma unroll
            for (int mf = 0; mf < 4; ++mf)
#pragma unroll
                for (int nf = 0; nf < 2; ++nf) {
                    acc1[mf][nf] = __builtin_amdgcn_mfma_f32_16x16x32_bf16(
                        af[mf], b1f[nf], acc1[mf][nf], 0, 0, 0);
                    acc3[mf][nf] = __builtin_amdgcn_mfma_f32_16x16x32_bf16(
                        af[mf], b3f[nf], acc3[mf][nf], 0, 0, 0);
                }
        }
        __syncthreads();
    }

#pragma unroll
    for (int mf = 0; mf < 4; ++mf) {
#pragma unroll
        for (int jj = 0; jj < 4; ++jj) {
            int rl = wm * 64 + mf * 16 + fkg * 4 + jj;
            int s = sl[rl];
            if (s < 0) continue;
            short* hp = H + (size_t)s * ldH + n0 + wn * 32 + frow;
#pragma unroll
            for (int nf = 0; nf < 2; ++nf)
                hp[nf * 16] = f2bf(silu1(acc1[mf][nf][jj]) * acc3[mf][nf][jj]);
        }
    }
}

// ---------------- fused out-GEMM (shared -> Y fp32, routed -> H2 bf16) ----------------
__global__ __launch_bounds__(256) void moe_out_kernel(
    const short* __restrict__ Hs, const short* __restrict__ swt2, float* __restrict__ Y,
    const short* __restrict__ Hr, const short* __restrict__ rwt2, short* __restrict__ H2,
    const int* __restrict__ expert_list, const int* __restrict__ expert_count)
{
    __shared__ char SMEM[24576];
    __shared__ int sl[128];
    int bid = blockIdx.x, tid = threadIdx.x;
    int xcd = bid & 7, qq = bid >> 3, mtile = qq & 15, gq = qq >> 4;
    int g = gq * 8 + xcd;
    if (g >= 288) return;
    const short *A, *B;
    int ldAb, NIT, n0, count;
    bool gather;
    const int* list = nullptr;
    int m0 = mtile * 128;
    if (g < 32) {
        gather = false; count = N_TOK;
        A = Hs; ldAb = FS_DIM * 2; NIT = 44; B = swt2; n0 = g * 64;
    } else {
        int g2 = g - 32, e = g2 >> 5;
        n0 = (g2 & 31) * 64;
        gather = true;
        count = expert_count[e];
        if (m0 >= count) return;
        list = expert_list + e * N_TOK;
        A = Hr; ldAb = F_DIM * 2; NIT = 22;
        B = rwt2 + (size_t)e * D_DIM * F_DIM;
    }
    if (tid < 128) {
        int rr = m0 + tid;
        sl[tid] = gather ? ((rr < count) ? list[rr] : -1) : rr;
    }
    __syncthreads();

    int l = tid & 63, w = tid >> 6;
    char* As = SMEM;             // 16K
    char* Bs = SMEM + 16384;     // 8K

    const char* aS[4];
#pragma unroll
    for (int j = 0; j < 4; ++j) {
        int r = (w * 4 + j) * 8 + (l >> 3);
        int s = sl[r];
        int arow = gather ? (s >= 0 ? s : 0) : s;
        aS[j] = (const char*)A + (size_t)arow * ldAb + (((l & 7) ^ (r & 7)) << 4);
    }
    const char* bS[2];
#pragma unroll
    for (int j = 0; j < 2; ++j) {
        int r = (w * 2 + j) * 8 + (l >> 3);
        bS[j] = (const char*)B + (size_t)(n0 + r) * ldAb + (((l & 7) ^ (r & 7)) << 4);
    }

    int wm = w >> 1, wn = w & 1, frow = l & 15, fkg = l >> 4;
    f32x4 acc[4][2];
#pragma unroll
    for (int i = 0; i < 4; ++i)
#pragma unroll
        for (int j = 0; j < 2; ++j) acc[i][j] = (f32x4)0.f;

    for (int it = 0; it < NIT; ++it) {
        int kb = it << 7;
#pragma unroll
        for (int j = 0; j < 4; ++j)
            async_copy16(aS[j] + kb, As + (w * 4 + j) * 1024);
#pragma unroll
        for (int j = 0; j < 2; ++j)
            async_copy16(bS[j] + kb, Bs + (w * 2 + j) * 1024);
        __syncthreads();
#pragma unroll
        for (int kk = 0; kk < 2; ++kk) {
            bf16x8 af[4], bf[2];
#pragma unroll
            for (int mf = 0; mf < 4; ++mf) {
                int r = wm * 64 + mf * 16 + frow;
                af[mf] = *reinterpret_cast<const bf16x8*>(
                    As + r * 128 + ((((kk << 2) | fkg) ^ (r & 7)) << 4));
            }
#pragma unroll
            for (int nf = 0; nf < 2; ++nf) {
                int r = wn * 32 + nf * 16 + frow;
                bf[nf] = *reinterpret_cast<const bf16x8*>(
                    Bs + r * 128 + ((((kk << 2) | fkg) ^ (r & 7)) << 4));
            }
#pragma unroll
            for (int mf = 0; mf < 4; ++mf)
#pragma unroll
                for (int nf = 0; nf < 2; ++nf)
                    acc[mf][nf] = __builtin_amdgcn_mfma_f32_16x16x32_bf16(
                        af[mf], bf[nf], acc[mf][nf], 0, 0, 0);
        }
        __syncthreads();
    }

#pragma unroll
    for (int mf = 0; mf < 4; ++mf) {
#pragma unroll
        for (int jj = 0; jj < 4; ++jj) {
            int rl = wm * 64 + mf * 16 + fkg * 4 + jj;
            int s = sl[rl];
            if (s < 0) continue;
            int col = n0 + wn * 32 + frow;
            if (!gather) {
                float* op = Y + (size_t)s * D_DIM + col;
#pragma unroll
                for (int nf = 0; nf < 2; ++nf)
                    op[nf * 16] = acc[mf][nf][jj];
            } else {
                short* op = H2 + (size_t)s * D_DIM + col;
#pragma unroll
                for (int nf = 0; nf < 2; ++nf)
                    op[nf * 16] = f2bf(acc[mf][nf][jj]);
            }
        }
    }
}

// ---------------- combine (H2 bf16) ----------------
__global__ __launch_bounds__(256) void combine_kernel(
    float* __restrict__ Y, const short* __restrict__ H2,
    const float* __restrict__ assign_w)
{
    int tok = blockIdx.x, tid = threadIdx.x;
    float w0 = assign_w[2 * tok];
    float w1 = assign_w[2 * tok + 1];
    const short* h0 = H2 + (size_t)(2 * tok) * D_DIM + tid * 8;
    const short* h1 = h0 + D_DIM;
    bf16x8 a = *reinterpret_cast<const bf16x8*>(h0);
    bf16x8 b = *reinterpret_cast<const bf16x8*>(h1);
    float* y = Y + (size_t)tok * D_DIM + tid * 8;
    float4 y0 = *reinterpret_cast<float4*>(y);
    float4 y1 = *reinterpret_cast<float4*>(y + 4);
    y0.x = fmaf(w0, bf2f(a[0]), fmaf(w1, bf2f(b[0]), y0.x));
    y0.y = fmaf(w0, bf2f(a[1]), fmaf(w1, bf2f(b[1]), y0.y));
    y0.z = fmaf(w0, bf2f(a[2]), fmaf(w1, bf2f(b[2]), y0.z));
    y0.w = fmaf(w0, bf2f(a[3]), fmaf(w1, bf2f(b[3]), y0.w));
    y1.x = fmaf(w0, bf2f(a[4]), fmaf(w1, bf2f(b[4]), y1.x));
    y1.y = fmaf(w0, bf2f(a[5]), fmaf(w1, bf2f(b[5]), y1.y));
    y1.z = fmaf(w0, bf2f(a[6]), fmaf(w1, bf2f(b[6]), y1.z));
    y1.w = fmaf(w0, bf2f(a[7]), fmaf(w1, bf2f(b[7]), y1.w));
    *reinterpret_cast<float4*>(y) = y0;
    *reinterpret_cast<float4*>(y + 4) = y1;
}

extern "C" void kernel_launch(void* const* d_in, const int* in_sizes, int n_in,
                              void* d_out, int out_size, void* d_ws, size_t ws_size,
                              hipStream_t stream) {
    const float* x   = (const float*)d_in[0];
    const float* gw  = (const float*)d_in[1];
    const float* sw1 = (const float*)d_in[2];
    const float* sw2 = (const float*)d_in[3];
    const float* sw3 = (const float*)d_in[4];
    const float* rw1 = (const float*)d_in[5];
    const float* rw2 = (const float*)d_in[6];
    const float* rw3 = (const float*)d_in[7];
    float* Y = (float*)d_out;

    char* ws = (char*)d_ws;
    float* assign_w     = (float*)(ws);
    int*   expert_count = (int*)(ws + 16384);
    int*   expert_list  = (int*)(ws + 16384 + 256);

    const size_t XB_OFF   = 131072;
    const size_t SWT1_OFF = XB_OFF + 8388608ull;
    const size_t SWT3_OFF = SWT1_OFF + 11534336ull;
    const size_t SWT2_OFF = SWT3_OFF + 11534336ull;
    const size_t RWT1_OFF = SWT2_OFF + 11534336ull;
    const size_t RWT3_OFF = RWT1_OFF + 46137344ull;
    const size_t RWT2_OFF = RWT3_OFF + 46137344ull;
    const size_t HS_OFF   = RWT2_OFF + 46137344ull;
    const size_t HR_OFF   = HS_OFF + 11534336ull;
    const size_t H2_OFF   = HR_OFF + 11534336ull;   // bf16 [4096][2048] = 16.8 MB

    short* Xb   = (short*)(ws + XB_OFF);
    short* swt1 = (short*)(ws + SWT1_OFF);
    short* swt3 = (short*)(ws + SWT3_OFF);
    short* swt2 = (short*)(ws + SWT2_OFF);
    short* rwt1 = (short*)(ws + RWT1_OFF);
    short* rwt3 = (short*)(ws + RWT3_OFF);
    short* rwt2 = (short*)(ws + RWT2_OFF);
    short* Hs   = (short*)(ws + HS_OFF);
    short* Hr   = (short*)(ws + HR_OFF);
    short* H2   = (short*)(ws + H2_OFF);

    hipMemsetAsync(expert_count, 0, E_NUM * sizeof(int), stream);

    // gate(512) + cvt_x(2048) + sw1(1408) + sw3(1408) + rw1(5632) + rw3(5632)
    prep_kernel<<<16640, 256, 0, stream>>>(
        x, gw, assign_w, expert_count, expert_list, Xb,
        sw1, swt1, sw3, swt3, rw1, rwt1, rw3, rwt3);

    // GEMM blocks 3584 (220 groups: 44 shared-in + 176 routed-in, XCD-mapped)
    // + sw2 transpose (1408) + rw2 transpose (5632)
    moe_in_kernel<<<10624, 256, 0, stream>>>(
        Xb, swt1, swt3, Hs, rwt1, rwt3, Hr,
        expert_list, expert_count, sw2, swt2, rw2, rwt2);

    // 288 groups: 32 shared-out + 256 routed-out
    moe_out_kernel<<<4608, 256, 0, stream>>>(
        Hs, swt2, Y, Hr, rwt2, H2, expert_list, expert_count);

    combine_kernel<<<N_TOK, 256, 0, stream>>>(Y, H2, assign_w);
}